// Round 17
// baseline (446.924 us; speedup 1.0000x reference)
//
#include <hip/hip_runtime.h>
#include <math.h>

#define NN 20000
#define NE 320000
#define TS 16
#define HG 64
#define HTT 128
#define NG 384   // 3*HT
#define LN_EPS 1e-5f
#define ASTR 1032   // LDS agg row stride in halfs (516 dwords ≡ 4 mod 32)

typedef __attribute__((ext_vector_type(8))) _Float16 f16x8;
typedef __attribute__((ext_vector_type(4))) float f32x4;

__device__ __forceinline__ float wave_sum64(float v) {
  #pragma unroll
  for (int off = 32; off > 0; off >>= 1) v += __shfl_xor(v, off, 64);
  return v;
}
__device__ __forceinline__ float quad_sum16(float v) {
  #pragma unroll
  for (int off = 1; off < 16; off <<= 1) v += __shfl_xor(v, off, 64);
  return v;
}
__device__ __forceinline__ float fast_sigmoid(float x) {
  return __builtin_amdgcn_rcpf(1.f + __expf(-x));
}
__device__ __forceinline__ float fast_tanh(float x) {
  float e = __expf(-2.f * fabsf(x));
  float th = (1.f - e) * __builtin_amdgcn_rcpf(1.f + e);
  return copysignf(th, x);
}

// ---------------- fused setup: cnt-zero + weight cvts + moments + x transpose ----------------
__global__ __launch_bounds__(256) void k_setup(
    const float* __restrict__ x_seq, float* __restrict__ xT,
    const float* __restrict__ Wih, _Float16* __restrict__ WihF,
    const float* __restrict__ Whh, _Float16* __restrict__ WhhF,
    const float* __restrict__ Wl1, const float* __restrict__ Wr1,
    _Float16* __restrict__ Wchi, _Float16* __restrict__ Wclo,
    const float* __restrict__ Wl0, const float* __restrict__ Wr0,
    const float* __restrict__ b0, const float* __restrict__ g0,
    const float* __restrict__ be0, float* __restrict__ P,
    int* __restrict__ cnt) {
  int gid = blockIdx.x * 256 + threadIdx.x;
  int stride = gridDim.x * 256;
  for (int i = gid; i < NN * TS; i += stride) {
    int t = i / NN, n = i - t * NN;
    xT[n * 16 + t] = x_seq[i];
  }
  for (int i = gid; i < NG * HG; i += stride) WihF[i] = (_Float16)Wih[i];
  for (int i = gid; i < NG * HTT; i += stride) WhhF[i] = (_Float16)Whh[i];
  for (int i = gid; i < HG * 128; i += stride) {
    int n = i >> 7, k = i & 127;
    float x = (k < HG) ? Wl1[k * HG + n] : Wr1[(k - HG) * HG + n];
    _Float16 h = (_Float16)x;
    Wchi[i] = h;
    Wclo[i] = (_Float16)(x - (float)h);
  }
  for (int i = gid; i < NN; i += stride) cnt[i] = 0;
  if (blockIdx.x == 0 && threadIdx.x < 64) {
    int f = threadIdx.x;
    float u = Wl0[f], v = Wr0[f], c = b0[f], g = g0[f];
    float um = wave_sum64(u) * (1.f / 64.f);
    float vm = wave_sum64(v) * (1.f / 64.f);
    float cm = wave_sum64(c) * (1.f / 64.f);
    float uc = u - um, vc = v - vm, cc = c - cm;
    float muu = wave_sum64(uc * uc) * (1.f / 64.f);
    float mvv = wave_sum64(vc * vc) * (1.f / 64.f);
    float mcc = wave_sum64(cc * cc) * (1.f / 64.f);
    float muv = wave_sum64(uc * vc) * (1.f / 64.f);
    float muc = wave_sum64(uc * cc) * (1.f / 64.f);
    float mvc = wave_sum64(vc * cc) * (1.f / 64.f);
    P[f] = uc * g; P[64 + f] = vc * g; P[128 + f] = cc * g; P[192 + f] = be0[f];
    if (f == 0) {
      P[256] = muu; P[257] = mvv; P[258] = mcc;
      P[259] = muv; P[260] = muc; P[261] = mvc;
    }
  }
}

__global__ void k_hist(const int* __restrict__ dst, int* cnt) {
  int e = blockIdx.x * blockDim.x + threadIdx.x;
  if (e < NE) atomicAdd(&cnt[dst[e]], 1);
}

// 1-pass scan: thread handles 20 elements in registers
__global__ void k_scan(int* cnt, int* row_ptr, float* deg_inv) {
  __shared__ int s[1024];
  const int PER = 20;
  int tid = threadIdx.x;
  int base = tid * PER;
  int vloc[PER], dloc[PER];
  int sum = 0;
  #pragma unroll
  for (int j = 0; j < PER; j++) {
    int n = base + j;
    int d = (n < NN) ? cnt[n] : 0;
    vloc[j] = sum;
    dloc[j] = d;
    sum += d;
  }
  s[tid] = sum;
  __syncthreads();
  for (int off = 1; off < 1024; off <<= 1) {
    int t = (tid >= off) ? s[tid - off] : 0;
    __syncthreads();
    s[tid] += t;
    __syncthreads();
  }
  int excl = s[tid] - sum;
  #pragma unroll
  for (int j = 0; j < PER; j++) {
    int n = base + j;
    if (n < NN) {
      int rp = excl + vloc[j];
      row_ptr[n] = rp;
      cnt[n] = rp;
      int d = dloc[j];
      deg_inv[n] = 1.0f / (float)((d > 1) ? d : 1);
    }
  }
  if (tid == 1023) row_ptr[NN] = s[1023];
}

__global__ void k_fill(const int* __restrict__ src, const int* __restrict__ dst,
                       int* cursor, int* col) {
  int e = blockIdx.x * blockDim.x + threadIdx.x;
  if (e < NE) {
    int p = atomicAdd(&cursor[dst[e]], 1);
    col[p] = src[e];
  }
}

// ---------------- fused agg0 + h0: wave per node ----------------
// Step 1 (agg): 4 edge-groups of 16 lanes, lane&15 = t; after the two xor
// reductions EVERY lane holds the edge-sum for t = lane&15.
// Step 2 (h0): lane handles chunks {lane, lane+64} of the node's 1024-half row;
// agg/x for the chunk's t fetched via __shfl.
__global__ __launch_bounds__(256) void k_h0_fused(
    const float* __restrict__ xT,
    const int* __restrict__ row_ptr, const int* __restrict__ col,
    const float* __restrict__ deg_inv,
    const float* __restrict__ P,
    _Float16* __restrict__ h0r) {   // [n][16][64]
  int lane = threadIdx.x & 63;
  int n = blockIdx.x * 4 + (threadIdx.x >> 6);
  int grp = lane >> 4, tl = lane & 15;
  int beg = row_ptr[n];
  int deg = row_ptr[n + 1] - beg;
  float s0 = 0.f, s1 = 0.f;
  int iters = (deg + 7) >> 3;
  for (int it = 0; it < iters; it++) {
    int e0 = it * 8 + grp, e1 = it * 8 + 4 + grp;
    bool v0 = e0 < deg, v1 = e1 < deg;
    int i0 = v0 ? e0 : 0, i1 = v1 ? e1 : 0;
    int c0 = col[beg + i0];
    int c1 = col[beg + i1];
    float x0 = xT[c0 * 16 + tl];
    float x1 = xT[c1 * 16 + tl];
    s0 += v0 ? x0 : 0.f;
    s1 += v1 ? x1 : 0.f;
  }
  float s = s0 + s1;
  s += __shfl_xor(s, 16, 64);
  s += __shfl_xor(s, 32, 64);
  float aggv = s * deg_inv[n];          // lane holds agg for t = lane&15
  float xv = xT[n * 16 + tl];           // lane holds x for t = lane&15
  float muu = P[256], mvv = P[257], mcc = P[258];
  float muv = P[259], muc = P[260], mvc = P[261];
  #pragma unroll
  for (int half = 0; half < 2; half++) {
    int c = lane + half * 64;           // chunk index 0..127
    int t = c >> 3, f8 = (c & 7) * 8;
    float a = __shfl(aggv, t, 64);
    float x = __shfl(xv, t, 64);
    float var = a * a * muu + x * x * mvv + mcc
              + 2.f * (a * x * muv + a * muc + x * mvc);
    float rstd = rsqrtf(var + LN_EPS);
    f16x8 o;
    #pragma unroll
    for (int j = 0; j < 8; j++) {
      int f = f8 + j;
      float d = a * P[f] + x * P[64 + f] + P[128 + f];
      o[j] = (_Float16)fmaxf(d * rstd + P[192 + f], 0.f);
    }
    *(f16x8*)&h0r[(size_t)n * 1024 + c * 8] = o;
  }
}

// ---------------- FUSED gather + SAGE-1 GEMM + LN + ReLU ----------------
__global__ __launch_bounds__(256, 4) void k_sage_fused(
    const _Float16* __restrict__ h0r,     // [n][16][64]
    const int* __restrict__ row_ptr, const int* __restrict__ col,
    const float* __restrict__ deg_inv,
    const _Float16* __restrict__ Wchi, const _Float16* __restrict__ Wclo, // [64][128]
    const float* __restrict__ b1, const float* __restrict__ g1, const float* __restrict__ be1,
    _Float16* __restrict__ Ht_all) {      // [t][n][64]
  __shared__ _Float16 aggL[16 * ASTR];    // 33 KB
  int tid = threadIdx.x;
  int lane = tid & 63, wave = tid >> 6;
  int col16 = lane & 15, quad = lane >> 4;
  int m0 = blockIdx.x * 16;

  // ---- Phase A: gather 4 nodes per wave (8-edge unroll, 16 loads in flight) ----
  for (int i = 0; i < 4; i++) {
    int nl = wave * 4 + i;
    int n = m0 + nl;
    int beg = row_ptr[n];
    int deg = row_ptr[n + 1] - beg;
    const f16x8 z = {0,0,0,0,0,0,0,0};
    f16x8 aH0 = z, aH1 = z, aH2 = z, aH3 = z;
    f16x8 aL0 = z, aL1 = z, aL2 = z, aL3 = z;
    int e = 0;
    for (; e + 8 <= deg; e += 8) {
      int c0 = col[beg + e + 0], c1 = col[beg + e + 1];
      int c2 = col[beg + e + 2], c3 = col[beg + e + 3];
      int c4 = col[beg + e + 4], c5 = col[beg + e + 5];
      int c6 = col[beg + e + 6], c7 = col[beg + e + 7];
      const f16x8* p0 = (const f16x8*)(h0r + (size_t)c0 * 1024);
      const f16x8* p1 = (const f16x8*)(h0r + (size_t)c1 * 1024);
      const f16x8* p2 = (const f16x8*)(h0r + (size_t)c2 * 1024);
      const f16x8* p3 = (const f16x8*)(h0r + (size_t)c3 * 1024);
      const f16x8* p4 = (const f16x8*)(h0r + (size_t)c4 * 1024);
      const f16x8* p5 = (const f16x8*)(h0r + (size_t)c5 * 1024);
      const f16x8* p6 = (const f16x8*)(h0r + (size_t)c6 * 1024);
      const f16x8* p7 = (const f16x8*)(h0r + (size_t)c7 * 1024);
      f16x8 d0a = p0[lane], d0b = p0[lane + 64];
      f16x8 d1a = p1[lane], d1b = p1[lane + 64];
      f16x8 d2a = p2[lane], d2b = p2[lane + 64];
      f16x8 d3a = p3[lane], d3b = p3[lane + 64];
      f16x8 d4a = p4[lane], d4b = p4[lane + 64];
      f16x8 d5a = p5[lane], d5b = p5[lane + 64];
      f16x8 d6a = p6[lane], d6b = p6[lane + 64];
      f16x8 d7a = p7[lane], d7b = p7[lane + 64];
      aH0 += d0a; aL0 += d0b;
      aH1 += d1a; aL1 += d1b;
      aH2 += d2a; aL2 += d2b;
      aH3 += d3a; aL3 += d3b;
      aH0 += d4a; aL0 += d4b;
      aH1 += d5a; aL1 += d5b;
      aH2 += d6a; aL2 += d6b;
      aH3 += d7a; aL3 += d7b;
    }
    for (; e + 4 <= deg; e += 4) {
      int c0 = col[beg + e + 0], c1 = col[beg + e + 1];
      int c2 = col[beg + e + 2], c3 = col[beg + e + 3];
      const f16x8* p0 = (const f16x8*)(h0r + (size_t)c0 * 1024);
      const f16x8* p1 = (const f16x8*)(h0r + (size_t)c1 * 1024);
      const f16x8* p2 = (const f16x8*)(h0r + (size_t)c2 * 1024);
      const f16x8* p3 = (const f16x8*)(h0r + (size_t)c3 * 1024);
      f16x8 d0a = p0[lane], d0b = p0[lane + 64];
      f16x8 d1a = p1[lane], d1b = p1[lane + 64];
      f16x8 d2a = p2[lane], d2b = p2[lane + 64];
      f16x8 d3a = p3[lane], d3b = p3[lane + 64];
      aH0 += d0a; aL0 += d0b;
      aH1 += d1a; aL1 += d1b;
      aH2 += d2a; aL2 += d2b;
      aH3 += d3a; aL3 += d3b;
    }
    for (; e < deg; e++) {
      int c = col[beg + e];
      const f16x8* p = (const f16x8*)(h0r + (size_t)c * 1024);
      aH0 += p[lane]; aL0 += p[lane + 64];
    }
    float di = deg_inv[n];
    f16x8 o0, o1;
    #pragma unroll
    for (int j = 0; j < 8; j++) {
      o0[j] = (_Float16)((((float)aH0[j] + (float)aH1[j]) +
                          ((float)aH2[j] + (float)aH3[j])) * di);
      o1[j] = (_Float16)((((float)aL0[j] + (float)aL1[j]) +
                          ((float)aL2[j] + (float)aL3[j])) * di);
    }
    *(f16x8*)&aggL[nl * ASTR + lane * 8] = o0;
    *(f16x8*)&aggL[nl * ASTR + 512 + lane * 8] = o1;
  }
  __syncthreads();

  // ---- Phase B: 4 t-slices per wave ----
  for (int ts = 0; ts < 4; ts++) {
    int t = wave * 4 + ts;
    f32x4 acc[4];
    #pragma unroll
    for (int nt = 0; nt < 4; nt++) acc[nt] = (f32x4){0.f, 0.f, 0.f, 0.f};

    #pragma unroll
    for (int kk = 0; kk < 2; kk++) {
      f16x8 ah = *(const f16x8*)&aggL[col16 * ASTR + t * 64 + kk * 32 + quad * 8];
      #pragma unroll
      for (int nt = 0; nt < 4; nt++) {
        int nf = nt * 16 + col16;
        f16x8 bh = *(const f16x8*)&Wchi[nf * 128 + kk * 32 + quad * 8];
        f16x8 bl = *(const f16x8*)&Wclo[nf * 128 + kk * 32 + quad * 8];
        acc[nt] = __builtin_amdgcn_mfma_f32_16x16x32_f16(ah, bh, acc[nt], 0, 0, 0);
        acc[nt] = __builtin_amdgcn_mfma_f32_16x16x32_f16(ah, bl, acc[nt], 0, 0, 0);
      }
    }
    #pragma unroll
    for (int kk = 0; kk < 2; kk++) {
      f16x8 ah = *(const f16x8*)&h0r[(size_t)(m0 + col16) * 1024 + t * 64 + kk * 32 + quad * 8];
      #pragma unroll
      for (int nt = 0; nt < 4; nt++) {
        int nf = nt * 16 + col16;
        f16x8 bh = *(const f16x8*)&Wchi[nf * 128 + 64 + kk * 32 + quad * 8];
        f16x8 bl = *(const f16x8*)&Wclo[nf * 128 + 64 + kk * 32 + quad * 8];
        acc[nt] = __builtin_amdgcn_mfma_f32_16x16x32_f16(ah, bh, acc[nt], 0, 0, 0);
        acc[nt] = __builtin_amdgcn_mfma_f32_16x16x32_f16(ah, bl, acc[nt], 0, 0, 0);
      }
    }

    float bias[4], gg[4], bb[4];
    #pragma unroll
    for (int nt = 0; nt < 4; nt++) {
      int nf = nt * 16 + col16;
      bias[nt] = b1[nf]; gg[nt] = g1[nf]; bb[nt] = be1[nf];
    }
    #pragma unroll
    for (int r = 0; r < 4; r++) {
      float v[4];
      #pragma unroll
      for (int nt = 0; nt < 4; nt++) v[nt] = acc[nt][r] + bias[nt];
      float s = (v[0] + v[1]) + (v[2] + v[3]);
      float mu = quad_sum16(s) * (1.f / 64.f);
      float sq = 0.f;
      #pragma unroll
      for (int nt = 0; nt < 4; nt++) { v[nt] -= mu; sq += v[nt] * v[nt]; }
      float var = quad_sum16(sq) * (1.f / 64.f);
      float rstd = rsqrtf(var + LN_EPS);
      int m = m0 + quad * 4 + r;
      size_t base = ((size_t)t * NN + m) * HG;
      #pragma unroll
      for (int nt = 0; nt < 4; nt++) {
        float o = fmaxf(v[nt] * rstd * gg[nt] + bb[nt], 0.f);
        Ht_all[base + nt * 16 + col16] = (_Float16)o;
      }
    }
  }
}

// ---------------- persistent GRU (R13 version — known-good 105 us) ----------------
__global__ __launch_bounds__(256, 2) void k_gru_all(
    const _Float16* __restrict__ Ht_all,   // [t][n][64]
    const _Float16* __restrict__ WihF,     // 384 x 64 fp16
    const _Float16* __restrict__ WhhF,     // 384 x 128 fp16
    const float* __restrict__ bih, const float* __restrict__ bhh,
    const float* __restrict__ headW, const float* __restrict__ headb,
    float* __restrict__ out) {
  __shared__ _Float16 WihL[NG * 64];       // 48 KB swizzled
  __shared__ _Float16 hL[2][32 * 128];     // 2 x 8 KB swizzled
  __shared__ float yL[4][32];

  int tid = threadIdx.x;
  int lane = tid & 63, wave = tid >> 6;
  int col16 = lane & 15, quad = lane >> 4;
  int m0 = blockIdx.x * 32;
  int gb = 2 * wave;

  for (int i = tid; i < NG * 8; i += 256) {
    int g = i >> 3, k8 = i & 7;
    *(f16x8*)&WihL[g * 64 + ((k8 + g) & 7) * 8] = *(const f16x8*)&WihF[g * 64 + k8 * 8];
  }
  for (int i = tid; i < 2 * 32 * 128; i += 256) hL[0][i] = (_Float16)0.f;

  int gts[6];
  #pragma unroll
  for (int t6 = 0; t6 < 6; t6++)
    gts[t6] = (t6 < 2) ? (gb + t6) : (t6 < 4) ? (8 + gb + t6 - 2) : (16 + gb + t6 - 4);

  f16x8 wgh[4][6];
  #pragma unroll
  for (int kk = 0; kk < 4; kk++)
    #pragma unroll
    for (int t6 = 0; t6 < 6; t6++)
      wgh[kk][t6] = *(const f16x8*)&WhhF[(size_t)(gts[t6] * 16 + col16) * HTT + kk * 32 + quad * 8];

  int jj[2]; float bR[2], bZ[2], bNi[2], bNh[2], hw[2];
  int waddr[2][4][2];
  #pragma unroll
  for (int js = 0; js < 2; js++) {
    int j = (gb + js) * 16 + col16;
    jj[js] = j;
    bR[js]  = bih[j] + bhh[j];
    bZ[js]  = bih[HTT + j] + bhh[HTT + j];
    bNi[js] = bih[2 * HTT + j];
    bNh[js] = bhh[2 * HTT + j];
    hw[js]  = headW[j];
    #pragma unroll
    for (int mt = 0; mt < 2; mt++)
      #pragma unroll
      for (int r = 0; r < 4; r++) {
        int row = mt * 16 + quad * 4 + r;
        waddr[mt][r][js] = row * 128 + (((j >> 3) + row) & 15) * 8 + (j & 7);
      }
  }
  float hreg[2][4][2];
  #pragma unroll
  for (int mt = 0; mt < 2; mt++)
    #pragma unroll
    for (int r = 0; r < 4; r++) { hreg[mt][r][0] = 0.f; hreg[mt][r][1] = 0.f; }

  size_t aoff[2][2];
  #pragma unroll
  for (int kk = 0; kk < 2; kk++)
    #pragma unroll
    for (int mt = 0; mt < 2; mt++)
      aoff[kk][mt] = (size_t)(m0 + mt * 16 + col16) * HG + kk * 32 + quad * 8;

  __syncthreads();

  for (int t = 0; t < TS; t++) {
    const _Float16* hcur = hL[t & 1];
    _Float16* hnxt = hL[(t + 1) & 1];

    f32x4 acc[8][2];
    #pragma unroll
    for (int a = 0; a < 8; a++) {
      acc[a][0] = (f32x4){0.f, 0.f, 0.f, 0.f};
      acc[a][1] = (f32x4){0.f, 0.f, 0.f, 0.f};
    }

    const _Float16* AH = Ht_all + (size_t)t * NN * HG;
    f16x8 gah[2][2];
    #pragma unroll
    for (int kk = 0; kk < 2; kk++)
      #pragma unroll
      for (int mt = 0; mt < 2; mt++)
        gah[kk][mt] = *(const f16x8*)&AH[aoff[kk][mt]];

    #pragma unroll
    for (int kk = 0; kk < 4; kk++) {
      f16x8 ah[2];
      #pragma unroll
      for (int mt = 0; mt < 2; mt++) {
        int row = mt * 16 + col16;
        int k8 = kk * 4 + quad;
        ah[mt] = *(const f16x8*)&hcur[row * 128 + ((k8 + row) & 15) * 8];
      }
      #pragma unroll
      for (int t6 = 0; t6 < 6; t6++) {
        int ai = (t6 < 4) ? t6 : t6 + 2;
        #pragma unroll
        for (int mt = 0; mt < 2; mt++)
          acc[ai][mt] = __builtin_amdgcn_mfma_f32_16x16x32_f16(ah[mt], wgh[kk][t6], acc[ai][mt], 0, 0, 0);
      }
    }
    #pragma unroll
    for (int kk = 0; kk < 2; kk++) {
      #pragma unroll
      for (int t6 = 0; t6 < 6; t6++) {
        int g = gts[t6] * 16 + col16;
        int k8 = kk * 4 + quad;
        f16x8 b = *(const f16x8*)&WihL[g * 64 + ((k8 + g) & 7) * 8];
        #pragma unroll
        for (int mt = 0; mt < 2; mt++)
          acc[t6][mt] = __builtin_amdgcn_mfma_f32_16x16x32_f16(gah[kk][mt], b, acc[t6][mt], 0, 0, 0);
      }
    }

    #pragma unroll
    for (int mt = 0; mt < 2; mt++) {
      #pragma unroll
      for (int r = 0; r < 4; r++) {
        #pragma unroll
        for (int js = 0; js < 2; js++) {
          float R  = acc[0 + js][mt][r] + bR[js];
          float Z  = acc[2 + js][mt][r] + bZ[js];
          float Ni = acc[4 + js][mt][r] + bNi[js];
          float Nh = acc[6 + js][mt][r] + bNh[js];
          float rg = fast_sigmoid(R);
          float zg = fast_sigmoid(Z);
          float nn = fast_tanh(Ni + rg * Nh);
          float hn = nn + zg * (hreg[mt][r][js] - nn);
          hreg[mt][r][js] = hn;
          hnxt[waddr[mt][r][js]] = (_Float16)hn;
        }
      }
    }
    __syncthreads();
  }

  #pragma unroll
  for (int mt = 0; mt < 2; mt++) {
    #pragma unroll
    for (int r = 0; r < 4; r++) {
      float py = hreg[mt][r][0] * hw[0] + hreg[mt][r][1] * hw[1];
      py = quad_sum16(py);
      if (col16 == 0) yL[wave][mt * 16 + quad * 4 + r] = py;
    }
  }
  __syncthreads();
  if (tid < 32)
    out[m0 + tid] = yL[0][tid] + yL[1][tid] + yL[2][tid] + yL[3][tid] + headb[0];
}

extern "C" void kernel_launch(void* const* d_in, const int* in_sizes, int n_in,
                              void* d_out, int out_size, void* d_ws, size_t ws_size,
                              hipStream_t stream) {
  const float* x_seq = (const float*)d_in[0];
  const int*   edge  = (const int*)d_in[1];
  const float* Wl0   = (const float*)d_in[2];
  const float* Wr0   = (const float*)d_in[3];
  const float* b0    = (const float*)d_in[4];
  const float* g0    = (const float*)d_in[5];
  const float* be0   = (const float*)d_in[6];
  const float* Wl1   = (const float*)d_in[7];
  const float* Wr1   = (const float*)d_in[8];
  const float* b1    = (const float*)d_in[9];
  const float* g1    = (const float*)d_in[10];
  const float* be1   = (const float*)d_in[11];
  const float* Wih   = (const float*)d_in[12];
  const float* Whh   = (const float*)d_in[13];
  const float* bih   = (const float*)d_in[14];
  const float* bhh   = (const float*)d_in[15];
  const float* headW = (const float*)d_in[16];
  const float* headb = (const float*)d_in[17];
  float* out = (float*)d_out;

  const int* srcp = edge;
  const int* dstp = edge + NE;

  char* ws = (char*)d_ws;
  size_t off = 0;
  auto alloc = [&](size_t bytes) -> void* {
    void* p = ws + off;
    off += (bytes + 255) & ~(size_t)255;
    return p;
  };
  int*   cnt     = (int*)alloc(NN * 4);
  int*   row_ptr = (int*)alloc((NN + 1) * 4);
  int*   col     = (int*)alloc(NE * 4);
  float* deg_inv = (float*)alloc(NN * 4);
  float* xT      = (float*)alloc((size_t)NN * TS * 4);
  float* P       = (float*)alloc(512 * 4);
  _Float16* h0r  = (_Float16*)alloc((size_t)NN * 1024 * 2);        // 41 MB [n][16][64]
  _Float16* Ht_all = (_Float16*)alloc((size_t)TS * NN * HG * 2);   // 41 MB [t][n][64]
  _Float16* WihF = (_Float16*)alloc((size_t)NG * HG * 2);
  _Float16* WhhF = (_Float16*)alloc((size_t)NG * HTT * 2);
  _Float16* Wchi = (_Float16*)alloc((size_t)HG * 128 * 2);
  _Float16* Wclo = (_Float16*)alloc((size_t)HG * 128 * 2);
  (void)ws_size; (void)in_sizes; (void)n_in; (void)out_size;

  k_setup<<<1250, 256, 0, stream>>>(x_seq, xT, Wih, WihF, Whh, WhhF,
                                    Wl1, Wr1, Wchi, Wclo,
                                    Wl0, Wr0, b0, g0, be0, P, cnt);
  k_hist<<<(NE + 255) / 256, 256, 0, stream>>>(dstp, cnt);
  k_scan<<<1, 1024, 0, stream>>>(cnt, row_ptr, deg_inv);
  k_fill<<<(NE + 255) / 256, 256, 0, stream>>>(srcp, dstp, cnt, col);
  k_h0_fused<<<NN / 4, 256, 0, stream>>>(xT, row_ptr, col, deg_inv, P, h0r);
  k_sage_fused<<<NN / 16, 256, 0, stream>>>(h0r, row_ptr, col, deg_inv,
                                            Wchi, Wclo, b1, g1, be1, Ht_all);
  k_gru_all<<<NN / 32, 256, 0, stream>>>(Ht_all, WihF, WhhF, bih, bhh,
                                         headW, headb, out);
}

// Round 18
// 396.219 us; speedup vs baseline: 1.1280x; 1.1280x over previous
//
#include <hip/hip_runtime.h>
#include <math.h>

#define NN 20000
#define NE 320000
#define TS 16
#define HG 64
#define HTT 128
#define NG 384   // 3*HT
#define LN_EPS 1e-5f
#define ASTR 1032   // LDS agg row stride in halfs (516 dwords ≡ 4 mod 32)

typedef __attribute__((ext_vector_type(8))) _Float16 f16x8;
typedef __attribute__((ext_vector_type(4))) float f32x4;

__device__ __forceinline__ float wave_sum64(float v) {
  #pragma unroll
  for (int off = 32; off > 0; off >>= 1) v += __shfl_xor(v, off, 64);
  return v;
}
__device__ __forceinline__ float quad_sum16(float v) {
  #pragma unroll
  for (int off = 1; off < 16; off <<= 1) v += __shfl_xor(v, off, 64);
  return v;
}
__device__ __forceinline__ float fast_sigmoid(float x) {
  return __builtin_amdgcn_rcpf(1.f + __expf(-x));
}
__device__ __forceinline__ float fast_tanh(float x) {
  float e = __expf(-2.f * fabsf(x));
  float th = (1.f - e) * __builtin_amdgcn_rcpf(1.f + e);
  return copysignf(th, x);
}

// ---------------- fused setup: cnt-zero + weight cvts + moments + x transpose ----------------
__global__ __launch_bounds__(256) void k_setup(
    const float* __restrict__ x_seq, float* __restrict__ xT,
    const float* __restrict__ Wih, _Float16* __restrict__ WihF,
    const float* __restrict__ Whh, _Float16* __restrict__ WhhF,
    const float* __restrict__ Wl1, const float* __restrict__ Wr1,
    _Float16* __restrict__ Wchi, _Float16* __restrict__ Wclo,
    const float* __restrict__ Wl0, const float* __restrict__ Wr0,
    const float* __restrict__ b0, const float* __restrict__ g0,
    const float* __restrict__ be0, float* __restrict__ P,
    int* __restrict__ cnt) {
  int gid = blockIdx.x * 256 + threadIdx.x;
  int stride = gridDim.x * 256;
  for (int i = gid; i < NN * TS; i += stride) {
    int t = i / NN, n = i - t * NN;
    xT[n * 16 + t] = x_seq[i];
  }
  for (int i = gid; i < NG * HG; i += stride) WihF[i] = (_Float16)Wih[i];
  for (int i = gid; i < NG * HTT; i += stride) WhhF[i] = (_Float16)Whh[i];
  for (int i = gid; i < HG * 128; i += stride) {
    int n = i >> 7, k = i & 127;
    float x = (k < HG) ? Wl1[k * HG + n] : Wr1[(k - HG) * HG + n];
    _Float16 h = (_Float16)x;
    Wchi[i] = h;
    Wclo[i] = (_Float16)(x - (float)h);
  }
  for (int i = gid; i < NN; i += stride) cnt[i] = 0;
  if (blockIdx.x == 0 && threadIdx.x < 64) {
    int f = threadIdx.x;
    float u = Wl0[f], v = Wr0[f], c = b0[f], g = g0[f];
    float um = wave_sum64(u) * (1.f / 64.f);
    float vm = wave_sum64(v) * (1.f / 64.f);
    float cm = wave_sum64(c) * (1.f / 64.f);
    float uc = u - um, vc = v - vm, cc = c - cm;
    float muu = wave_sum64(uc * uc) * (1.f / 64.f);
    float mvv = wave_sum64(vc * vc) * (1.f / 64.f);
    float mcc = wave_sum64(cc * cc) * (1.f / 64.f);
    float muv = wave_sum64(uc * vc) * (1.f / 64.f);
    float muc = wave_sum64(uc * cc) * (1.f / 64.f);
    float mvc = wave_sum64(vc * cc) * (1.f / 64.f);
    P[f] = uc * g; P[64 + f] = vc * g; P[128 + f] = cc * g; P[192 + f] = be0[f];
    if (f == 0) {
      P[256] = muu; P[257] = mvv; P[258] = mcc;
      P[259] = muv; P[260] = muc; P[261] = mvc;
    }
  }
}

__global__ void k_hist(const int* __restrict__ dst, int* cnt) {
  int e = blockIdx.x * blockDim.x + threadIdx.x;
  if (e < NE) atomicAdd(&cnt[dst[e]], 1);
}

// 1-pass scan: thread handles 20 elements in registers
__global__ void k_scan(int* cnt, int* row_ptr, float* deg_inv) {
  __shared__ int s[1024];
  const int PER = 20;
  int tid = threadIdx.x;
  int base = tid * PER;
  int vloc[PER], dloc[PER];
  int sum = 0;
  #pragma unroll
  for (int j = 0; j < PER; j++) {
    int n = base + j;
    int d = (n < NN) ? cnt[n] : 0;
    vloc[j] = sum;
    dloc[j] = d;
    sum += d;
  }
  s[tid] = sum;
  __syncthreads();
  for (int off = 1; off < 1024; off <<= 1) {
    int t = (tid >= off) ? s[tid - off] : 0;
    __syncthreads();
    s[tid] += t;
    __syncthreads();
  }
  int excl = s[tid] - sum;
  #pragma unroll
  for (int j = 0; j < PER; j++) {
    int n = base + j;
    if (n < NN) {
      int rp = excl + vloc[j];
      row_ptr[n] = rp;
      cnt[n] = rp;
      int d = dloc[j];
      deg_inv[n] = 1.0f / (float)((d > 1) ? d : 1);
    }
  }
  if (tid == 1023) row_ptr[NN] = s[1023];
}

__global__ void k_fill(const int* __restrict__ src, const int* __restrict__ dst,
                       int* cursor, int* col) {
  int e = blockIdx.x * blockDim.x + threadIdx.x;
  if (e < NE) {
    int p = atomicAdd(&cursor[dst[e]], 1);
    col[p] = src[e];
  }
}

// ---------------- fused agg0 + h0: wave per node ----------------
__global__ __launch_bounds__(256) void k_h0_fused(
    const float* __restrict__ xT,
    const int* __restrict__ row_ptr, const int* __restrict__ col,
    const float* __restrict__ deg_inv,
    const float* __restrict__ P,
    _Float16* __restrict__ h0r) {   // [n][16][64]
  int lane = threadIdx.x & 63;
  int n = blockIdx.x * 4 + (threadIdx.x >> 6);
  int grp = lane >> 4, tl = lane & 15;
  int beg = row_ptr[n];
  int deg = row_ptr[n + 1] - beg;
  float s0 = 0.f, s1 = 0.f;
  int iters = (deg + 7) >> 3;
  for (int it = 0; it < iters; it++) {
    int e0 = it * 8 + grp, e1 = it * 8 + 4 + grp;
    bool v0 = e0 < deg, v1 = e1 < deg;
    int i0 = v0 ? e0 : 0, i1 = v1 ? e1 : 0;
    int c0 = col[beg + i0];
    int c1 = col[beg + i1];
    float x0 = xT[c0 * 16 + tl];
    float x1 = xT[c1 * 16 + tl];
    s0 += v0 ? x0 : 0.f;
    s1 += v1 ? x1 : 0.f;
  }
  float s = s0 + s1;
  s += __shfl_xor(s, 16, 64);
  s += __shfl_xor(s, 32, 64);
  float aggv = s * deg_inv[n];          // lane holds agg for t = lane&15
  float xv = xT[n * 16 + tl];           // lane holds x for t = lane&15
  float muu = P[256], mvv = P[257], mcc = P[258];
  float muv = P[259], muc = P[260], mvc = P[261];
  #pragma unroll
  for (int half = 0; half < 2; half++) {
    int c = lane + half * 64;           // chunk index 0..127
    int t = c >> 3, f8 = (c & 7) * 8;
    float a = __shfl(aggv, t, 64);
    float x = __shfl(xv, t, 64);
    float var = a * a * muu + x * x * mvv + mcc
              + 2.f * (a * x * muv + a * muc + x * mvc);
    float rstd = rsqrtf(var + LN_EPS);
    f16x8 o;
    #pragma unroll
    for (int j = 0; j < 8; j++) {
      int f = f8 + j;
      float d = a * P[f] + x * P[64 + f] + P[128 + f];
      o[j] = (_Float16)fmaxf(d * rstd + P[192 + f], 0.f);
    }
    *(f16x8*)&h0r[(size_t)n * 1024 + c * 8] = o;
  }
}

// ---------------- FUSED gather + SAGE-1 GEMM + LN + ReLU ----------------
// NOTE: plain launch_bounds(256). R17's (256,4) capped VGPR at 64 -> gather
// accumulators spilled (WRITE 40->105 MB, FETCH 310->426 MB, 124->165 us).
__global__ __launch_bounds__(256) void k_sage_fused(
    const _Float16* __restrict__ h0r,     // [n][16][64]
    const int* __restrict__ row_ptr, const int* __restrict__ col,
    const float* __restrict__ deg_inv,
    const _Float16* __restrict__ Wchi, const _Float16* __restrict__ Wclo, // [64][128]
    const float* __restrict__ b1, const float* __restrict__ g1, const float* __restrict__ be1,
    _Float16* __restrict__ Ht_all) {      // [t][n][64]
  __shared__ _Float16 aggL[16 * ASTR];    // 33 KB
  int tid = threadIdx.x;
  int lane = tid & 63, wave = tid >> 6;
  int col16 = lane & 15, quad = lane >> 4;
  int m0 = blockIdx.x * 16;

  // ---- Phase A: gather 4 nodes per wave (8-edge unroll, 16 loads in flight) ----
  for (int i = 0; i < 4; i++) {
    int nl = wave * 4 + i;
    int n = m0 + nl;
    int beg = row_ptr[n];
    int deg = row_ptr[n + 1] - beg;
    const f16x8 z = {0,0,0,0,0,0,0,0};
    f16x8 aH0 = z, aH1 = z, aH2 = z, aH3 = z;
    f16x8 aL0 = z, aL1 = z, aL2 = z, aL3 = z;
    int e = 0;
    for (; e + 8 <= deg; e += 8) {
      int c0 = col[beg + e + 0], c1 = col[beg + e + 1];
      int c2 = col[beg + e + 2], c3 = col[beg + e + 3];
      int c4 = col[beg + e + 4], c5 = col[beg + e + 5];
      int c6 = col[beg + e + 6], c7 = col[beg + e + 7];
      const f16x8* p0 = (const f16x8*)(h0r + (size_t)c0 * 1024);
      const f16x8* p1 = (const f16x8*)(h0r + (size_t)c1 * 1024);
      const f16x8* p2 = (const f16x8*)(h0r + (size_t)c2 * 1024);
      const f16x8* p3 = (const f16x8*)(h0r + (size_t)c3 * 1024);
      const f16x8* p4 = (const f16x8*)(h0r + (size_t)c4 * 1024);
      const f16x8* p5 = (const f16x8*)(h0r + (size_t)c5 * 1024);
      const f16x8* p6 = (const f16x8*)(h0r + (size_t)c6 * 1024);
      const f16x8* p7 = (const f16x8*)(h0r + (size_t)c7 * 1024);
      f16x8 d0a = p0[lane], d0b = p0[lane + 64];
      f16x8 d1a = p1[lane], d1b = p1[lane + 64];
      f16x8 d2a = p2[lane], d2b = p2[lane + 64];
      f16x8 d3a = p3[lane], d3b = p3[lane + 64];
      f16x8 d4a = p4[lane], d4b = p4[lane + 64];
      f16x8 d5a = p5[lane], d5b = p5[lane + 64];
      f16x8 d6a = p6[lane], d6b = p6[lane + 64];
      f16x8 d7a = p7[lane], d7b = p7[lane + 64];
      aH0 += d0a; aL0 += d0b;
      aH1 += d1a; aL1 += d1b;
      aH2 += d2a; aL2 += d2b;
      aH3 += d3a; aL3 += d3b;
      aH0 += d4a; aL0 += d4b;
      aH1 += d5a; aL1 += d5b;
      aH2 += d6a; aL2 += d6b;
      aH3 += d7a; aL3 += d7b;
    }
    for (; e + 4 <= deg; e += 4) {
      int c0 = col[beg + e + 0], c1 = col[beg + e + 1];
      int c2 = col[beg + e + 2], c3 = col[beg + e + 3];
      const f16x8* p0 = (const f16x8*)(h0r + (size_t)c0 * 1024);
      const f16x8* p1 = (const f16x8*)(h0r + (size_t)c1 * 1024);
      const f16x8* p2 = (const f16x8*)(h0r + (size_t)c2 * 1024);
      const f16x8* p3 = (const f16x8*)(h0r + (size_t)c3 * 1024);
      f16x8 d0a = p0[lane], d0b = p0[lane + 64];
      f16x8 d1a = p1[lane], d1b = p1[lane + 64];
      f16x8 d2a = p2[lane], d2b = p2[lane + 64];
      f16x8 d3a = p3[lane], d3b = p3[lane + 64];
      aH0 += d0a; aL0 += d0b;
      aH1 += d1a; aL1 += d1b;
      aH2 += d2a; aL2 += d2b;
      aH3 += d3a; aL3 += d3b;
    }
    for (; e < deg; e++) {
      int c = col[beg + e];
      const f16x8* p = (const f16x8*)(h0r + (size_t)c * 1024);
      aH0 += p[lane]; aL0 += p[lane + 64];
    }
    float di = deg_inv[n];
    f16x8 o0, o1;
    #pragma unroll
    for (int j = 0; j < 8; j++) {
      o0[j] = (_Float16)((((float)aH0[j] + (float)aH1[j]) +
                          ((float)aH2[j] + (float)aH3[j])) * di);
      o1[j] = (_Float16)((((float)aL0[j] + (float)aL1[j]) +
                          ((float)aL2[j] + (float)aL3[j])) * di);
    }
    *(f16x8*)&aggL[nl * ASTR + lane * 8] = o0;
    *(f16x8*)&aggL[nl * ASTR + 512 + lane * 8] = o1;
  }
  __syncthreads();

  // ---- Phase B: 4 t-slices per wave ----
  for (int ts = 0; ts < 4; ts++) {
    int t = wave * 4 + ts;
    f32x4 acc[4];
    #pragma unroll
    for (int nt = 0; nt < 4; nt++) acc[nt] = (f32x4){0.f, 0.f, 0.f, 0.f};

    #pragma unroll
    for (int kk = 0; kk < 2; kk++) {
      f16x8 ah = *(const f16x8*)&aggL[col16 * ASTR + t * 64 + kk * 32 + quad * 8];
      #pragma unroll
      for (int nt = 0; nt < 4; nt++) {
        int nf = nt * 16 + col16;
        f16x8 bh = *(const f16x8*)&Wchi[nf * 128 + kk * 32 + quad * 8];
        f16x8 bl = *(const f16x8*)&Wclo[nf * 128 + kk * 32 + quad * 8];
        acc[nt] = __builtin_amdgcn_mfma_f32_16x16x32_f16(ah, bh, acc[nt], 0, 0, 0);
        acc[nt] = __builtin_amdgcn_mfma_f32_16x16x32_f16(ah, bl, acc[nt], 0, 0, 0);
      }
    }
    #pragma unroll
    for (int kk = 0; kk < 2; kk++) {
      f16x8 ah = *(const f16x8*)&h0r[(size_t)(m0 + col16) * 1024 + t * 64 + kk * 32 + quad * 8];
      #pragma unroll
      for (int nt = 0; nt < 4; nt++) {
        int nf = nt * 16 + col16;
        f16x8 bh = *(const f16x8*)&Wchi[nf * 128 + 64 + kk * 32 + quad * 8];
        f16x8 bl = *(const f16x8*)&Wclo[nf * 128 + 64 + kk * 32 + quad * 8];
        acc[nt] = __builtin_amdgcn_mfma_f32_16x16x32_f16(ah, bh, acc[nt], 0, 0, 0);
        acc[nt] = __builtin_amdgcn_mfma_f32_16x16x32_f16(ah, bl, acc[nt], 0, 0, 0);
      }
    }

    float bias[4], gg[4], bb[4];
    #pragma unroll
    for (int nt = 0; nt < 4; nt++) {
      int nf = nt * 16 + col16;
      bias[nt] = b1[nf]; gg[nt] = g1[nf]; bb[nt] = be1[nf];
    }
    #pragma unroll
    for (int r = 0; r < 4; r++) {
      float v[4];
      #pragma unroll
      for (int nt = 0; nt < 4; nt++) v[nt] = acc[nt][r] + bias[nt];
      float s = (v[0] + v[1]) + (v[2] + v[3]);
      float mu = quad_sum16(s) * (1.f / 64.f);
      float sq = 0.f;
      #pragma unroll
      for (int nt = 0; nt < 4; nt++) { v[nt] -= mu; sq += v[nt] * v[nt]; }
      float var = quad_sum16(sq) * (1.f / 64.f);
      float rstd = rsqrtf(var + LN_EPS);
      int m = m0 + quad * 4 + r;
      size_t base = ((size_t)t * NN + m) * HG;
      #pragma unroll
      for (int nt = 0; nt < 4; nt++) {
        float o = fmaxf(v[nt] * rstd * gg[nt] + bb[nt], 0.f);
        Ht_all[base + nt * 16 + col16] = (_Float16)o;
      }
    }
  }
}

// ---------------- persistent GRU (R13 version — known-good 105 us) ----------------
__global__ __launch_bounds__(256, 2) void k_gru_all(
    const _Float16* __restrict__ Ht_all,   // [t][n][64]
    const _Float16* __restrict__ WihF,     // 384 x 64 fp16
    const _Float16* __restrict__ WhhF,     // 384 x 128 fp16
    const float* __restrict__ bih, const float* __restrict__ bhh,
    const float* __restrict__ headW, const float* __restrict__ headb,
    float* __restrict__ out) {
  __shared__ _Float16 WihL[NG * 64];       // 48 KB swizzled
  __shared__ _Float16 hL[2][32 * 128];     // 2 x 8 KB swizzled
  __shared__ float yL[4][32];

  int tid = threadIdx.x;
  int lane = tid & 63, wave = tid >> 6;
  int col16 = lane & 15, quad = lane >> 4;
  int m0 = blockIdx.x * 32;
  int gb = 2 * wave;

  for (int i = tid; i < NG * 8; i += 256) {
    int g = i >> 3, k8 = i & 7;
    *(f16x8*)&WihL[g * 64 + ((k8 + g) & 7) * 8] = *(const f16x8*)&WihF[g * 64 + k8 * 8];
  }
  for (int i = tid; i < 2 * 32 * 128; i += 256) hL[0][i] = (_Float16)0.f;

  int gts[6];
  #pragma unroll
  for (int t6 = 0; t6 < 6; t6++)
    gts[t6] = (t6 < 2) ? (gb + t6) : (t6 < 4) ? (8 + gb + t6 - 2) : (16 + gb + t6 - 4);

  f16x8 wgh[4][6];
  #pragma unroll
  for (int kk = 0; kk < 4; kk++)
    #pragma unroll
    for (int t6 = 0; t6 < 6; t6++)
      wgh[kk][t6] = *(const f16x8*)&WhhF[(size_t)(gts[t6] * 16 + col16) * HTT + kk * 32 + quad * 8];

  int jj[2]; float bR[2], bZ[2], bNi[2], bNh[2], hw[2];
  int waddr[2][4][2];
  #pragma unroll
  for (int js = 0; js < 2; js++) {
    int j = (gb + js) * 16 + col16;
    jj[js] = j;
    bR[js]  = bih[j] + bhh[j];
    bZ[js]  = bih[HTT + j] + bhh[HTT + j];
    bNi[js] = bih[2 * HTT + j];
    bNh[js] = bhh[2 * HTT + j];
    hw[js]  = headW[j];
    #pragma unroll
    for (int mt = 0; mt < 2; mt++)
      #pragma unroll
      for (int r = 0; r < 4; r++) {
        int row = mt * 16 + quad * 4 + r;
        waddr[mt][r][js] = row * 128 + (((j >> 3) + row) & 15) * 8 + (j & 7);
      }
  }
  float hreg[2][4][2];
  #pragma unroll
  for (int mt = 0; mt < 2; mt++)
    #pragma unroll
    for (int r = 0; r < 4; r++) { hreg[mt][r][0] = 0.f; hreg[mt][r][1] = 0.f; }

  size_t aoff[2][2];
  #pragma unroll
  for (int kk = 0; kk < 2; kk++)
    #pragma unroll
    for (int mt = 0; mt < 2; mt++)
      aoff[kk][mt] = (size_t)(m0 + mt * 16 + col16) * HG + kk * 32 + quad * 8;

  __syncthreads();

  for (int t = 0; t < TS; t++) {
    const _Float16* hcur = hL[t & 1];
    _Float16* hnxt = hL[(t + 1) & 1];

    f32x4 acc[8][2];
    #pragma unroll
    for (int a = 0; a < 8; a++) {
      acc[a][0] = (f32x4){0.f, 0.f, 0.f, 0.f};
      acc[a][1] = (f32x4){0.f, 0.f, 0.f, 0.f};
    }

    const _Float16* AH = Ht_all + (size_t)t * NN * HG;
    f16x8 gah[2][2];
    #pragma unroll
    for (int kk = 0; kk < 2; kk++)
      #pragma unroll
      for (int mt = 0; mt < 2; mt++)
        gah[kk][mt] = *(const f16x8*)&AH[aoff[kk][mt]];

    #pragma unroll
    for (int kk = 0; kk < 4; kk++) {
      f16x8 ah[2];
      #pragma unroll
      for (int mt = 0; mt < 2; mt++) {
        int row = mt * 16 + col16;
        int k8 = kk * 4 + quad;
        ah[mt] = *(const f16x8*)&hcur[row * 128 + ((k8 + row) & 15) * 8];
      }
      #pragma unroll
      for (int t6 = 0; t6 < 6; t6++) {
        int ai = (t6 < 4) ? t6 : t6 + 2;
        #pragma unroll
        for (int mt = 0; mt < 2; mt++)
          acc[ai][mt] = __builtin_amdgcn_mfma_f32_16x16x32_f16(ah[mt], wgh[kk][t6], acc[ai][mt], 0, 0, 0);
      }
    }
    #pragma unroll
    for (int kk = 0; kk < 2; kk++) {
      #pragma unroll
      for (int t6 = 0; t6 < 6; t6++) {
        int g = gts[t6] * 16 + col16;
        int k8 = kk * 4 + quad;
        f16x8 b = *(const f16x8*)&WihL[g * 64 + ((k8 + g) & 7) * 8];
        #pragma unroll
        for (int mt = 0; mt < 2; mt++)
          acc[t6][mt] = __builtin_amdgcn_mfma_f32_16x16x32_f16(gah[kk][mt], b, acc[t6][mt], 0, 0, 0);
      }
    }

    #pragma unroll
    for (int mt = 0; mt < 2; mt++) {
      #pragma unroll
      for (int r = 0; r < 4; r++) {
        #pragma unroll
        for (int js = 0; js < 2; js++) {
          float R  = acc[0 + js][mt][r] + bR[js];
          float Z  = acc[2 + js][mt][r] + bZ[js];
          float Ni = acc[4 + js][mt][r] + bNi[js];
          float Nh = acc[6 + js][mt][r] + bNh[js];
          float rg = fast_sigmoid(R);
          float zg = fast_sigmoid(Z);
          float nn = fast_tanh(Ni + rg * Nh);
          float hn = nn + zg * (hreg[mt][r][js] - nn);
          hreg[mt][r][js] = hn;
          hnxt[waddr[mt][r][js]] = (_Float16)hn;
        }
      }
    }
    __syncthreads();
  }

  #pragma unroll
  for (int mt = 0; mt < 2; mt++) {
    #pragma unroll
    for (int r = 0; r < 4; r++) {
      float py = hreg[mt][r][0] * hw[0] + hreg[mt][r][1] * hw[1];
      py = quad_sum16(py);
      if (col16 == 0) yL[wave][mt * 16 + quad * 4 + r] = py;
    }
  }
  __syncthreads();
  if (tid < 32)
    out[m0 + tid] = yL[0][tid] + yL[1][tid] + yL[2][tid] + yL[3][tid] + headb[0];
}

extern "C" void kernel_launch(void* const* d_in, const int* in_sizes, int n_in,
                              void* d_out, int out_size, void* d_ws, size_t ws_size,
                              hipStream_t stream) {
  const float* x_seq = (const float*)d_in[0];
  const int*   edge  = (const int*)d_in[1];
  const float* Wl0   = (const float*)d_in[2];
  const float* Wr0   = (const float*)d_in[3];
  const float* b0    = (const float*)d_in[4];
  const float* g0    = (const float*)d_in[5];
  const float* be0   = (const float*)d_in[6];
  const float* Wl1   = (const float*)d_in[7];
  const float* Wr1   = (const float*)d_in[8];
  const float* b1    = (const float*)d_in[9];
  const float* g1    = (const float*)d_in[10];
  const float* be1   = (const float*)d_in[11];
  const float* Wih   = (const float*)d_in[12];
  const float* Whh   = (const float*)d_in[13];
  const float* bih   = (const float*)d_in[14];
  const float* bhh   = (const float*)d_in[15];
  const float* headW = (const float*)d_in[16];
  const float* headb = (const float*)d_in[17];
  float* out = (float*)d_out;

  const int* srcp = edge;
  const int* dstp = edge + NE;

  char* ws = (char*)d_ws;
  size_t off = 0;
  auto alloc = [&](size_t bytes) -> void* {
    void* p = ws + off;
    off += (bytes + 255) & ~(size_t)255;
    return p;
  };
  int*   cnt     = (int*)alloc(NN * 4);
  int*   row_ptr = (int*)alloc((NN + 1) * 4);
  int*   col     = (int*)alloc(NE * 4);
  float* deg_inv = (float*)alloc(NN * 4);
  float* xT      = (float*)alloc((size_t)NN * TS * 4);
  float* P       = (float*)alloc(512 * 4);
  _Float16* h0r  = (_Float16*)alloc((size_t)NN * 1024 * 2);        // 41 MB [n][16][64]
  _Float16* Ht_all = (_Float16*)alloc((size_t)TS * NN * HG * 2);   // 41 MB [t][n][64]
  _Float16* WihF = (_Float16*)alloc((size_t)NG * HG * 2);
  _Float16* WhhF = (_Float16*)alloc((size_t)NG * HTT * 2);
  _Float16* Wchi = (_Float16*)alloc((size_t)HG * 128 * 2);
  _Float16* Wclo = (_Float16*)alloc((size_t)HG * 128 * 2);
  (void)ws_size; (void)in_sizes; (void)n_in; (void)out_size;

  k_setup<<<1250, 256, 0, stream>>>(x_seq, xT, Wih, WihF, Whh, WhhF,
                                    Wl1, Wr1, Wchi, Wclo,
                                    Wl0, Wr0, b0, g0, be0, P, cnt);
  k_hist<<<(NE + 255) / 256, 256, 0, stream>>>(dstp, cnt);
  k_scan<<<1, 1024, 0, stream>>>(cnt, row_ptr, deg_inv);
  k_fill<<<(NE + 255) / 256, 256, 0, stream>>>(srcp, dstp, cnt, col);
  k_h0_fused<<<NN / 4, 256, 0, stream>>>(xT, row_ptr, col, deg_inv, P, h0r);
  k_sage_fused<<<NN / 16, 256, 0, stream>>>(h0r, row_ptr, col, deg_inv,
                                            Wchi, Wclo, b1, g1, be1, Ht_all);
  k_gru_all<<<NN / 32, 256, 0, stream>>>(Ht_all, WihF, WhhF, bih, bhh,
                                         headW, headb, out);
}